// Round 18
// baseline (48.827 us; speedup 1.0000x reference)
//
#include <hip/hip_runtime.h>
#include <math.h>

// WaveletLayerND: fused mexican-hat wavelet + grouped 3x3 conv (kernel 1),
// then 1x1 channel mix (kernel 2). B=4, O=I=32, H=W=128.
//
// Round 18: r17 (fdot2 ALU diet) with the type fix: cvt_pkrtz returns
// __fp16 ext_vector(2), so h2 must be __fp16-based (not _Float16).
// Theory unchanged: nine schedule variants all landed at ~38-40us =>
// ALU-throughput-limited; pk_fma_f32 is half-rate (4cy) while fdot2 does
// 2 MACs in 2cy with f32 accumulate. Pair the CHANNEL dim: taps for
// channels (A,B) = 9 fdot2/elem (was 18 pk_fma): 72->36 ALU cy/pair.
// psi stays packed f32 (exact); only psi + weights round to f16
// (err ~1e-3 << 0.059 threshold). Skeleton = r10 (tap basis, epilogue
// halo combine, 4-wave blocks, 2048 blocks). NO launch_bounds min-arg
// (r3/4/7: forced caps spill to scratch). mix1x1 p-split 2.

#define RSTRIP 8   // output rows per wave

typedef float v2f __attribute__((ext_vector_type(2)));
typedef __fp16 h2 __attribute__((ext_vector_type(2)));

static __device__ __forceinline__ float bperm(int addr, float v) {
  return __int_as_float(__builtin_amdgcn_ds_bpermute(addr, __float_as_int(v)));
}

__global__ __launch_bounds__(256) void wavelet_grouped_conv(
    const float* __restrict__ x,      // (B, I, H, W)
    const float* __restrict__ scale,  // (O*I)
    const float* __restrict__ trans,  // (O*I)
    const float* __restrict__ wconv,  // (O, I, 3, 3)
    float* __restrict__ y,            // (B, O, H, W) workspace
    float mhc)
{
  const int tid   = threadIdx.x;
  const int lane  = tid & 63;
  const int iq    = tid >> 6;          // 0..3: which i-quarter this wave owns
  const int strip = blockIdx.x;        // 0..15
  const int o     = blockIdx.y;        // 0..31
  const int b     = blockIdx.z;        // 0..3
  const int r0    = strip * RSTRIP;
  const int c0    = lane << 1;         // this thread's two columns

  // bpermute byte-addresses: lane-1 / lane+1 (mod 64) — epilogue only
  const int a_up = ((lane + 63) & 63) << 2;
  const int a_dn = ((lane +  1) & 63) << 2;
  const bool lane0  = (lane == 0);
  const bool lane63 = (lane == 63);

  // psi(sx) = fma(wq,K1,K2)*exp2(wq), wq = -(CC*sx)^2, CC^2 = 0.5*log2(e)
  const float C2 = 0.72134752044448170f;
  const float CC = 0.84932214f;
  const float K1 = -mhc / C2;
  const float K2 = -mhc;
  // edge-row variants fold the conv's zero padding (psi -> 0)
  const float rv0 = (r0 > 0) ? 1.f : 0.f;              // input row r0-1
  const float rv9 = (r0 + RSTRIP < 128) ? 1.f : 0.f;   // input row r0+8
  const float K1a = K1 * rv0, K2a = K2 * rv0;
  const float K1b = K1 * rv9, K2b = K2 * rv9;

  // per-tap accumulators (f32): out[c] = TL[c-1] + TC[c] + TR[c+1]
  v2f TL[RSTRIP], TC[RSTRIP], TR[RSTRIP];
#pragma unroll
  for (int r = 0; r < RSTRIP; ++r) {
    TL[r] = (v2f){0.f, 0.f}; TC[r] = (v2f){0.f, 0.f}; TR[r] = (v2f){0.f, 0.f};
  }

  // per-lane clamped element offsets for the 10 rows (computed once)
  int off[RSTRIP + 2];
#pragma unroll
  for (int j = 0; j < RSTRIP + 2; ++j) {
    const int row = min(max(r0 + j - 1, 0), 127);
    off[j] = row * 128 + c0;
  }

  const float* xb = x + (size_t)b * 32 * 16384;

#pragma unroll 1
  for (int pr = 0; pr < 4; ++pr) {
    const int chA = iq * 8 + 2 * pr;                     // wave-uniform
    const int oiA = __builtin_amdgcn_readfirstlane(o * 32 + chA);
    const int oiB = oiA + 1;
    const float rscA  = CC / scale[oiA];
    const float trscA = trans[oiA] * rscA;
    const float rscB  = CC / scale[oiB];
    const float trscB = trans[oiB] * rscB;
    // packed f16 weight pairs <wA_k, wB_k>
    const float* wpA = wconv + oiA * 9;
    const float* wpB = wconv + oiB * 9;
    h2 wpk[9];
#pragma unroll
    for (int k = 0; k < 9; ++k)
      wpk[k] = __builtin_amdgcn_cvt_pkrtz(wpA[k], wpB[k]);
    const float* baseA = xb + (size_t)chA * 16384;
    const float* baseB = baseA + 16384;

#pragma unroll
    for (int j = 0; j < RSTRIP + 2; ++j) {
      const float k1 = (j == 0) ? K1a : (j == RSTRIP + 1) ? K1b : K1;
      const float k2 = (j == 0) ? K2a : (j == RSTRIP + 1) ? K2b : K2;
      const v2f xA = *(const v2f*)(baseA + off[j]);
      const v2f xB = *(const v2f*)(baseB + off[j]);
      // psi (packed f32)
      const v2f vA = __builtin_elementwise_fma(xA, (v2f){rscA, rscA},
                                               (v2f){-trscA, -trscA});
      const v2f vB = __builtin_elementwise_fma(xB, (v2f){rscB, rscB},
                                               (v2f){-trscB, -trscB});
      const v2f wqA = -(vA * vA);
      const v2f wqB = -(vB * vB);
      v2f eA, eB;
      eA.x = __builtin_amdgcn_exp2f(wqA.x);
      eA.y = __builtin_amdgcn_exp2f(wqA.y);
      eB.x = __builtin_amdgcn_exp2f(wqB.x);
      eB.y = __builtin_amdgcn_exp2f(wqB.y);
      const v2f gA = __builtin_elementwise_fma(wqA, (v2f){k1, k1},
                                               (v2f){k2, k2}) * eA;
      const v2f gB = __builtin_elementwise_fma(wqB, (v2f){k1, k1},
                                               (v2f){k2, k2}) * eB;
      // channel-pair packs <psiA, psiB> for the two columns
      const h2 px = __builtin_amdgcn_cvt_pkrtz(gA.x, gB.x);
      const h2 py = __builtin_amdgcn_cvt_pkrtz(gA.y, gB.y);

#define TAP2(ACC, WK)                                                 \
      ACC.x = __builtin_amdgcn_fdot2(WK, px, ACC.x, false);           \
      ACC.y = __builtin_amdgcn_fdot2(WK, py, ACC.y, false);

      // input row ir=r0+j-1 feeds out rows t=j (w0x), j-1 (w1x), j-2 (w2x)
      if (j <= RSTRIP - 1) {
        TAP2(TL[j], wpk[0])
        TAP2(TC[j], wpk[1])
        TAP2(TR[j], wpk[2])
      }
      if (j >= 1 && j <= RSTRIP) {
        TAP2(TL[j-1], wpk[3])
        TAP2(TC[j-1], wpk[4])
        TAP2(TR[j-1], wpk[5])
      }
      if (j >= 2) {
        TAP2(TL[j-2], wpk[6])
        TAP2(TC[j-2], wpk[7])
        TAP2(TR[j-2], wpk[8])
      }
#undef TAP2
    }
  }

  // horizontal combine: out[c0]   = TL[c0-1] + TC[c0]   + TR[c0+1]
  //                     out[c0+1] = TL[c0]   + TC[c0+1] + TR[c0+2]
  v2f acc[RSTRIP];
#pragma unroll
  for (int r = 0; r < RSTRIP; ++r) {
    float pl = bperm(a_up, TL[r].y);
    float pr = bperm(a_dn, TR[r].x);
    if (lane0)  pl = 0.f;
    if (lane63) pr = 0.f;
    v2f v;
    v.x = pl      + TC[r].x + TR[r].y;
    v.y = TL[r].x + TC[r].y + pr;
    acc[r] = v;
  }

  // reduce the four i-quarters through LDS (lane-major; b64 2-way is free)
  __shared__ v2f red[3][RSTRIP][64];   // 12 KB
  if (iq != 0) {
#pragma unroll
    for (int r = 0; r < RSTRIP; ++r) red[iq - 1][r][lane] = acc[r];
  }
  __syncthreads();
  if (iq == 0) {
    float* yb = y + (((size_t)b * 32 + o) * 128 + r0) * 128 + c0;
#pragma unroll
    for (int r = 0; r < RSTRIP; ++r) {
      const v2f v = acc[r] + red[0][r][lane] + red[1][r][lane] + red[2][r][lane];
      *(v2f*)(yb + (size_t)r * 128) = v;
    }
  }
}

__global__ __launch_bounds__(256) void mix1x1(
    const float* __restrict__ y,    // (B, O, H*W)
    const float* __restrict__ fw,   // (O_out, O_in)
    float* __restrict__ out)        // (B, O, H*W)
{
  const int px = blockIdx.x * 256 + threadIdx.x;  // 0..16383
  const int b  = blockIdx.y;
  const int ph = blockIdx.z;                      // 0..1: output-half
  const float* yb = y + (size_t)b * 32 * 16384 + px;
  float v[32];
#pragma unroll
  for (int o = 0; o < 32; ++o) v[o] = yb[(size_t)o * 16384];
  float* ob = out + (size_t)b * 32 * 16384 + px;
#pragma unroll
  for (int p = 0; p < 16; ++p) {
    const int po = ph * 16 + p;
    float a = 0.f;
#pragma unroll
    for (int o = 0; o < 32; ++o) a = fmaf(fw[po * 32 + o], v[o], a);
    ob[(size_t)po * 16384] = a;
  }
}

extern "C" void kernel_launch(void* const* d_in, const int* in_sizes, int n_in,
                              void* d_out, int out_size, void* d_ws, size_t ws_size,
                              hipStream_t stream) {
  const float* x     = (const float*)d_in[0];
  const float* scale = (const float*)d_in[1];
  const float* trans = (const float*)d_in[2];
  const float* wconv = (const float*)d_in[3];
  const float* fw    = (const float*)d_in[4];
  float* out = (float*)d_out;
  float* y   = (float*)d_ws;   // 4*32*128*128 floats = 8.39 MB

  const float mhc = (float)(2.0 / (sqrt(3.0) * pow(M_PI, 0.25)));

  dim3 g1(128 / RSTRIP, 32, 4);  // (strip, o, b) = 2048 blocks x 256 thr
  wavelet_grouped_conv<<<g1, 256, 0, stream>>>(x, scale, trans, wconv, y, mhc);

  dim3 g2(16384 / 256, 4, 2);    // (pixel tiles, b, p-half)
  mix1x1<<<g2, 256, 0, stream>>>(y, fw, out);
}